// Round 1
// baseline (946.936 us; speedup 1.0000x reference)
//
#include <hip/hip_runtime.h>

#define D     128
#define NT    200000
#define NL    50000
#define ETA   1000000
#define EREV  1000000
#define ELL   500000
#define ELBL  500000

typedef __attribute__((ext_vector_type(8))) __bf16 bf16x8;
typedef __attribute__((ext_vector_type(4))) float f32x4;

__device__ inline bf16x8 cvt8(float4 a, float4 b)
{
    bf16x8 r;
    r[0] = (__bf16)a.x; r[1] = (__bf16)a.y; r[2] = (__bf16)a.z; r[3] = (__bf16)a.w;
    r[4] = (__bf16)b.x; r[5] = (__bf16)b.y; r[6] = (__bf16)b.z; r[7] = (__bf16)b.w;
    return r;
}

// ---------------------------------------------------------------------------
// Weight prep: 4 bf16 weight slots in [n][k] layout + bias_sum.
// Slot 0 = W_l_tl, 1 = W_r_tl, 2 = W_l_ll, 3 = W_r_tl + W_r_ll.
// ---------------------------------------------------------------------------
__global__ __launch_bounds__(256) void prep_weights(
    const float* __restrict__ Wl_tl, const float* __restrict__ Wr_tl,
    const float* __restrict__ Wl_ll, const float* __restrict__ Wr_ll,
    const float* __restrict__ b_tl, const float* __restrict__ b_ll,
    __bf16* __restrict__ Wb, float* __restrict__ bias_sum)
{
    int i = blockIdx.x * 256 + threadIdx.x;
    if (i < D * D) {
        Wb[i]             = (__bf16)Wl_tl[i];
        Wb[D * D + i]     = (__bf16)Wr_tl[i];
        Wb[2 * D * D + i] = (__bf16)Wl_ll[i];
        Wb[3 * D * D + i] = (__bf16)(Wr_tl[i] + Wr_ll[i]);
    }
    if (i < D) bias_sum[i] = b_tl[i] + b_ll[i];
}

// ---------------------------------------------------------------------------
// Degree count.
// ---------------------------------------------------------------------------
__global__ __launch_bounds__(256) void count_kernel(
    const int* __restrict__ dst, int* __restrict__ cnt, int E)
{
    int e = blockIdx.x * 256 + threadIdx.x;
    if (e >= E) return;
    atomicAdd(&cnt[dst[e]], 1);
}

// ---------------------------------------------------------------------------
// Order-free segment allocation: wave prefix-sum + one atomicAdd per wave.
// ---------------------------------------------------------------------------
__global__ __launch_bounds__(256) void alloc_kernel(
    const int* __restrict__ cnt, int* __restrict__ cur,
    int* __restrict__ gcnt, int n)
{
    int i = blockIdx.x * 256 + threadIdx.x;
    int lane = threadIdx.x & 63;
    int deg = (i < n) ? cnt[i] : 0;
    int incl = deg;
#pragma unroll
    for (int off = 1; off < 64; off <<= 1) {
        int v = __shfl_up(incl, off, 64);
        if (lane >= off) incl += v;
    }
    int excl = incl - deg;
    int total = __shfl(incl, 63, 64);
    int base = 0;
    if (lane == 63) base = atomicAdd(gcnt, total);
    base = __shfl(base, 63, 64);
    if (i < n) cur[i] = base + excl;
}

// ---------------------------------------------------------------------------
// CSR fill. After this, cur[row] == segment end.
// ---------------------------------------------------------------------------
__global__ __launch_bounds__(256) void fill_kernel(
    const int* __restrict__ src, const int* __restrict__ dst,
    const int* __restrict__ remap, int* __restrict__ cur,
    int* __restrict__ csr, int E)
{
    int e = blockIdx.x * 256 + threadIdx.x;
    if (e >= E) return;
    int s = src[e];
    if (remap) s = remap[s];
    int pos = atomicAdd(&cur[dst[e]], 1);
    csr[pos] = s;
}

// ---------------------------------------------------------------------------
// Segmented mean (ta path only): one wave per dst row, float2 per lane.
// ---------------------------------------------------------------------------
__global__ __launch_bounds__(256) void agg_kernel(
    const float* __restrict__ xsrc, const int* __restrict__ csr,
    const int* __restrict__ cnt, const int* __restrict__ cur,
    float* __restrict__ agg, int n)
{
    int row = blockIdx.x * 4 + (threadIdx.x >> 6);
    if (row >= n) return;
    int lane = threadIdx.x & 63;
    int deg = cnt[row];
    int end = cur[row];
    int e = end - deg;
    float accx = 0.f, accy = 0.f;
    for (; e + 1 < end; e += 2) {
        int s0 = csr[e], s1 = csr[e + 1];
        float2 v0 = *reinterpret_cast<const float2*>(xsrc + (size_t)s0 * D + lane * 2);
        float2 v1 = *reinterpret_cast<const float2*>(xsrc + (size_t)s1 * D + lane * 2);
        accx += v0.x + v1.x;
        accy += v0.y + v1.y;
    }
    if (e < end) {
        int s0 = csr[e];
        float2 v0 = *reinterpret_cast<const float2*>(xsrc + (size_t)s0 * D + lane * 2);
        accx += v0.x;
        accy += v0.y;
    }
    float r = 1.0f / fmaxf((float)deg, 1.0f);
    *reinterpret_cast<float2*>(agg + (size_t)row * D + lane * 2) =
        make_float2(accx * r, accy * r);
}

// ---------------------------------------------------------------------------
// Z = x_label @ {W_l_tl, W_l_ll}^T stored as bf16 [NL][128].
// 64 rows/block, 4 waves, each wave owns 16 rows x all 128 cols.
// By linearity mean(x_label[src]) @ W^T == mean(Z[src]) — so rev/ll
// aggregations become cheap bf16 gathers from a 12.8 MB L2-resident table.
// ---------------------------------------------------------------------------
__global__ __launch_bounds__(256) void z_label_gemm(
    const float* __restrict__ labelEmbed, const int* __restrict__ labelNodeId,
    const __bf16* __restrict__ Wb,
    __bf16* __restrict__ Zrev, __bf16* __restrict__ Zll)
{
    const int w = threadIdx.x >> 6;
    const int lane = threadIdx.x & 63;
    const int m15 = lane & 15, q = lane >> 4;
    const int rBase = blockIdx.x * 64 + w * 16;
    int rowA = rBase + m15;
    if (rowA >= NL) rowA = NL - 1;
    const int xr = labelNodeId[rowA];

    bf16x8 aE[4];
    const float* pe = labelEmbed + (size_t)xr * D + q * 8;
#pragma unroll
    for (int kc = 0; kc < 4; ++kc) {
        float4 f0 = *reinterpret_cast<const float4*>(pe + kc * 32);
        float4 f1 = *reinterpret_cast<const float4*>(pe + kc * 32 + 4);
        aE[kc] = cvt8(f0, f1);
    }

    const f32x4 z4 = {0.f, 0.f, 0.f, 0.f};
    f32x4 acc0[8], acc1[8];
#pragma unroll
    for (int nt = 0; nt < 8; ++nt) { acc0[nt] = z4; acc1[nt] = z4; }

    const __bf16* W0 = Wb;             // W_l_tl
    const __bf16* W2 = Wb + 2 * D * D; // W_l_ll
#pragma unroll
    for (int kc = 0; kc < 4; ++kc) {
#pragma unroll
        for (int nt = 0; nt < 8; ++nt) {
            int n = nt * 16 + m15;
            bf16x8 b0 = *reinterpret_cast<const bf16x8*>(W0 + n * D + kc * 32 + q * 8);
            bf16x8 b2 = *reinterpret_cast<const bf16x8*>(W2 + n * D + kc * 32 + q * 8);
            acc0[nt] = __builtin_amdgcn_mfma_f32_16x16x32_bf16(aE[kc], b0, acc0[nt], 0, 0, 0);
            acc1[nt] = __builtin_amdgcn_mfma_f32_16x16x32_bf16(aE[kc], b2, acc1[nt], 0, 0, 0);
        }
    }
#pragma unroll
    for (int nt = 0; nt < 8; ++nt) {
#pragma unroll
        for (int rg = 0; rg < 4; ++rg) {
            int row = rBase + q * 4 + rg;
            if (row < NL) {
                Zrev[(size_t)row * D + nt * 16 + m15] = (__bf16)acc0[nt][rg];
                Zll [(size_t)row * D + nt * 16 + m15] = (__bf16)acc1[nt][rg];
            }
        }
    }
}

// ---------------------------------------------------------------------------
// Title side: out = relu(x_title @ Wr_tl^T + b_tl + mean(Zrev[rev_src])).
// 64 rows/block (A-rows read ONCE), wave = 16 rows x 128 cols.
// rev aggregation fused into the epilogue: gathered bf16 scalar loads in
// C-fragment layout (col = nt*16+m15 per lane), 2-edge unrolled for ILP.
// ---------------------------------------------------------------------------
__global__ __launch_bounds__(256) void gemm_title_mfma(
    const float* __restrict__ xTitle, const __bf16* __restrict__ Wb,
    const float* __restrict__ b_tl, const __bf16* __restrict__ Zrev,
    const int* __restrict__ csrRev, const int* __restrict__ cntRev,
    const int* __restrict__ curRev, float* __restrict__ outTitle)
{
    const int w = threadIdx.x >> 6;
    const int lane = threadIdx.x & 63;
    const int m15 = lane & 15, q = lane >> 4;
    const int rBase = blockIdx.x * 64 + w * 16;
    const int rowA = rBase + m15;

    bf16x8 aX[4];
    const float* px = xTitle + (size_t)rowA * D + q * 8;
#pragma unroll
    for (int kc = 0; kc < 4; ++kc) {
        float4 g0 = *reinterpret_cast<const float4*>(px + kc * 32);
        float4 g1 = *reinterpret_cast<const float4*>(px + kc * 32 + 4);
        aX[kc] = cvt8(g0, g1);
    }

    const f32x4 z4 = {0.f, 0.f, 0.f, 0.f};
    f32x4 acc[8];
#pragma unroll
    for (int nt = 0; nt < 8; ++nt) acc[nt] = z4;

    const __bf16* W1 = Wb + D * D;     // W_r_tl
#pragma unroll
    for (int kc = 0; kc < 4; ++kc) {
#pragma unroll
        for (int nt = 0; nt < 8; ++nt) {
            int n = nt * 16 + m15;
            bf16x8 b1 = *reinterpret_cast<const bf16x8*>(W1 + n * D + kc * 32 + q * 8);
            acc[nt] = __builtin_amdgcn_mfma_f32_16x16x32_bf16(aX[kc], b1, acc[nt], 0, 0, 0);
        }
    }

    float bias[8];
#pragma unroll
    for (int nt = 0; nt < 8; ++nt) bias[nt] = b_tl[nt * 16 + m15];

#pragma unroll
    for (int rg = 0; rg < 4; ++rg) {
        int row = rBase + q * 4 + rg;
        int deg = cntRev[row];
        int end = curRev[row];
        int e = end - deg;
        float racc[8] = {0.f, 0.f, 0.f, 0.f, 0.f, 0.f, 0.f, 0.f};
        for (; e + 1 < end; e += 2) {
            int j0 = csrRev[e], j1 = csrRev[e + 1];
            const __bf16* z0 = Zrev + (size_t)j0 * D + m15;
            const __bf16* z1 = Zrev + (size_t)j1 * D + m15;
#pragma unroll
            for (int nt = 0; nt < 8; ++nt)
                racc[nt] += (float)z0[nt * 16] + (float)z1[nt * 16];
        }
        if (e < end) {
            int j0 = csrRev[e];
            const __bf16* z0 = Zrev + (size_t)j0 * D + m15;
#pragma unroll
            for (int nt = 0; nt < 8; ++nt)
                racc[nt] += (float)z0[nt * 16];
        }
        float rs = 1.0f / fmaxf((float)deg, 1.0f);
#pragma unroll
        for (int nt = 0; nt < 8; ++nt)
            outTitle[(size_t)row * D + nt * 16 + m15] =
                fmaxf(acc[nt][rg] + racc[nt] * rs + bias[nt], 0.0f);
    }
}

// ---------------------------------------------------------------------------
// Label side: out = relu(meanTa @ W_l_tl^T + x_label @ (Wr_tl+Wr_ll)^T
//                        + b_sum + mean(Zll[ll_src])).
// meanTa aliases outLabel (barrier between A-reads and C-writes, per-block
// rows are disjoint across blocks). ll aggregation fused into epilogue.
// ---------------------------------------------------------------------------
__global__ __launch_bounds__(256) void gemm_label_mfma(
    const float* __restrict__ meanTa, const float* __restrict__ labelEmbed,
    const int* __restrict__ labelNodeId, const __bf16* __restrict__ Wb,
    const float* __restrict__ bias_sum, const __bf16* __restrict__ Zll,
    const int* __restrict__ csrLl, const int* __restrict__ cntLl,
    const int* __restrict__ curLl, float* __restrict__ outLabel)
{
    const int w = threadIdx.x >> 6;
    const int lane = threadIdx.x & 63;
    const int m15 = lane & 15, q = lane >> 4;
    const int rBase = blockIdx.x * 64 + w * 16;
    int rowA = rBase + m15;
    if (rowA >= NL) rowA = NL - 1;       // clamp (partial last block)
    const int xr = labelNodeId[rowA];

    bf16x8 aT[4], aXl[4];
    const float* pt = meanTa + (size_t)rowA * D + q * 8;
    const float* pe = labelEmbed + (size_t)xr * D + q * 8;
#pragma unroll
    for (int kc = 0; kc < 4; ++kc) {
        float4 f0 = *reinterpret_cast<const float4*>(pt + kc * 32);
        float4 f1 = *reinterpret_cast<const float4*>(pt + kc * 32 + 4);
        aT[kc] = cvt8(f0, f1);
        float4 h0 = *reinterpret_cast<const float4*>(pe + kc * 32);
        float4 h1 = *reinterpret_cast<const float4*>(pe + kc * 32 + 4);
        aXl[kc] = cvt8(h0, h1);
    }
    __syncthreads();   // all meanTa reads complete before any outLabel write

    const f32x4 z4 = {0.f, 0.f, 0.f, 0.f};
    f32x4 acc[8];
#pragma unroll
    for (int nt = 0; nt < 8; ++nt) acc[nt] = z4;

    const __bf16* W0 = Wb;             // W_l_tl
    const __bf16* W3 = Wb + 3 * D * D; // W_r_tl + W_r_ll
#pragma unroll
    for (int kc = 0; kc < 4; ++kc) {
#pragma unroll
        for (int nt = 0; nt < 8; ++nt) {
            int n = nt * 16 + m15;
            bf16x8 b0 = *reinterpret_cast<const bf16x8*>(W0 + n * D + kc * 32 + q * 8);
            bf16x8 b3 = *reinterpret_cast<const bf16x8*>(W3 + n * D + kc * 32 + q * 8);
            acc[nt] = __builtin_amdgcn_mfma_f32_16x16x32_bf16(aT[kc], b0, acc[nt], 0, 0, 0);
            acc[nt] = __builtin_amdgcn_mfma_f32_16x16x32_bf16(aXl[kc], b3, acc[nt], 0, 0, 0);
        }
    }

    float bias[8];
#pragma unroll
    for (int nt = 0; nt < 8; ++nt) bias[nt] = bias_sum[nt * 16 + m15];

#pragma unroll
    for (int rg = 0; rg < 4; ++rg) {
        int row = rBase + q * 4 + rg;
        int rc = (row < NL) ? row : (NL - 1);
        int deg = cntLl[rc];
        int end = curLl[rc];
        int e = end - deg;
        float racc[8] = {0.f, 0.f, 0.f, 0.f, 0.f, 0.f, 0.f, 0.f};
        for (; e + 1 < end; e += 2) {
            int j0 = csrLl[e], j1 = csrLl[e + 1];
            const __bf16* z0 = Zll + (size_t)j0 * D + m15;
            const __bf16* z1 = Zll + (size_t)j1 * D + m15;
#pragma unroll
            for (int nt = 0; nt < 8; ++nt)
                racc[nt] += (float)z0[nt * 16] + (float)z1[nt * 16];
        }
        if (e < end) {
            int j0 = csrLl[e];
            const __bf16* z0 = Zll + (size_t)j0 * D + m15;
#pragma unroll
            for (int nt = 0; nt < 8; ++nt)
                racc[nt] += (float)z0[nt * 16];
        }
        float rs = 1.0f / fmaxf((float)deg, 1.0f);
        if (row < NL) {
#pragma unroll
            for (int nt = 0; nt < 8; ++nt)
                outLabel[(size_t)row * D + nt * 16 + m15] =
                    fmaxf(acc[nt][rg] + racc[nt] * rs + bias[nt], 0.0f);
        }
    }
}

// ---------------------------------------------------------------------------
// Supervision-edge dot products: 32 lanes per edge, float4 per lane.
// ---------------------------------------------------------------------------
__global__ __launch_bounds__(256) void pred_kernel(
    const float* __restrict__ outTitle, const float* __restrict__ outLabel,
    const int* __restrict__ elSrc, const int* __restrict__ elDst,
    float* __restrict__ pred, int E)
{
    int idx = blockIdx.x * 256 + threadIdx.x;
    int e = idx >> 5;
    if (e >= E) return;
    int l = idx & 31;
    int s = elSrc[e];
    int d = elDst[e];
    float4 a = *reinterpret_cast<const float4*>(outTitle + (size_t)s * D + l * 4);
    float4 b = *reinterpret_cast<const float4*>(outLabel + (size_t)d * D + l * 4);
    float v = a.x * b.x + a.y * b.y + a.z * b.z + a.w * b.w;
#pragma unroll
    for (int off = 16; off > 0; off >>= 1) v += __shfl_down(v, off, 32);
    if (l == 0) pred[e] = v;
}

// ---------------------------------------------------------------------------
extern "C" void kernel_launch(void* const* d_in, const int* in_sizes, int n_in,
                              void* d_out, int out_size, void* d_ws, size_t ws_size,
                              hipStream_t stream)
{
    const float* x_title       = (const float*)d_in[0];
    const float* label_embed   = (const float*)d_in[1];
    const float* W_l_tl        = (const float*)d_in[2];
    const float* b_l_tl        = (const float*)d_in[3];
    const float* W_r_tl        = (const float*)d_in[4];
    const float* W_l_ll        = (const float*)d_in[5];
    const float* b_l_ll        = (const float*)d_in[6];
    const float* W_r_ll        = (const float*)d_in[7];
    const int*   label_node_id = (const int*)d_in[8];
    const int*   ta_src        = (const int*)d_in[9];
    const int*   ta_dst        = (const int*)d_in[10];
    const int*   rev_src       = (const int*)d_in[11];
    const int*   rev_dst       = (const int*)d_in[12];
    const int*   ll_src        = (const int*)d_in[13];
    const int*   ll_dst        = (const int*)d_in[14];
    const int*   el_src        = (const int*)d_in[15];
    const int*   el_dst        = (const int*)d_in[16];

    float* out       = (float*)d_out;
    float* pred      = out;                        // [ELBL]
    float* out_title = out + ELBL;                 // [NT*D]
    float* out_label = out_title + (size_t)NT * D; // [NL*D] — doubles as meanTa

    // Workspace layout (~38.1 MB, same footprint as previous version).
    __bf16* Wb      = (__bf16*)d_ws;                       // 4*D*D bf16 = 128 KiB
    float*  bias_sum= (float*)(Wb + 4 * D * D);            // 128 floats
    __bf16* Zrev    = (__bf16*)(bias_sum + D);             // NL*D bf16 = 12.8 MB
    __bf16* Zll     = Zrev + (size_t)NL * D;               // NL*D bf16 = 12.8 MB
    int*    cntTa   = (int*)(Zll + (size_t)NL * D);        // NL
    int*    cntLl   = cntTa + NL;                          // NL
    int*    cntRev  = cntLl + NL;                          // NT
    int*    gcnt    = cntRev + NT;                         // 3
    int*    curTa   = gcnt + 3;                            // NL
    int*    curLl   = curTa + NL;                          // NL
    int*    curRev  = curLl + NL;                          // NT
    int*    csrTa   = curRev + NT;                         // ETA
    int*    csrLl   = csrTa + ETA;                         // ELL
    int*    csrRev  = csrLl + ELL;                         // EREV

    // Zero degree counters + the 3 global cursors (contiguous).
    hipMemsetAsync(cntTa, 0, (size_t)(NL + NL + NT + 3) * sizeof(int), stream);

    prep_weights<<<(D * D + 255) / 256, 256, 0, stream>>>(
        W_l_tl, W_r_tl, W_l_ll, W_r_ll, b_l_tl, b_l_ll, Wb, bias_sum);

    // Z tables (label rows through W_l_tl / W_l_ll), bf16.
    z_label_gemm<<<(NL + 63) / 64, 256, 0, stream>>>(
        label_embed, label_node_id, Wb, Zrev, Zll);

    // Degree histograms.
    count_kernel<<<(ETA  + 255) / 256, 256, 0, stream>>>(ta_dst,  cntTa,  ETA);
    count_kernel<<<(ELL  + 255) / 256, 256, 0, stream>>>(ll_dst,  cntLl,  ELL);
    count_kernel<<<(EREV + 255) / 256, 256, 0, stream>>>(rev_dst, cntRev, EREV);

    // Segment allocation (order-free, one atomic per wave).
    alloc_kernel<<<(NL + 255) / 256, 256, 0, stream>>>(cntTa,  curTa,  gcnt + 0, NL);
    alloc_kernel<<<(NL + 255) / 256, 256, 0, stream>>>(cntLl,  curLl,  gcnt + 1, NL);
    alloc_kernel<<<(NT + 255) / 256, 256, 0, stream>>>(cntRev, curRev, gcnt + 2, NT);

    // CSR fills. rev/ll store UNremapped label-row ids (Z is in x_label space).
    fill_kernel<<<(ETA  + 255) / 256, 256, 0, stream>>>(ta_src,  ta_dst,  nullptr, curTa,  csrTa,  ETA);
    fill_kernel<<<(ELL  + 255) / 256, 256, 0, stream>>>(ll_src,  ll_dst,  nullptr, curLl,  csrLl,  ELL);
    fill_kernel<<<(EREV + 255) / 256, 256, 0, stream>>>(rev_src, rev_dst, nullptr, curRev, csrRev, EREV);

    // ta segmented mean (fp32 gathers from x_title) → meanTa in out_label.
    agg_kernel<<<(NL + 3) / 4, 256, 0, stream>>>(
        x_title, csrTa, cntTa, curTa, out_label /*meanTa*/, NL);

    // Title GEMM with fused rev aggregation.
    gemm_title_mfma<<<NT / 64, 256, 0, stream>>>(
        x_title, Wb, b_l_tl, Zrev, csrRev, cntRev, curRev, out_title);

    // Label GEMM with fused ll aggregation (meanTa aliased in out_label).
    gemm_label_mfma<<<(NL + 63) / 64, 256, 0, stream>>>(
        out_label, label_embed, label_node_id, Wb, bias_sum,
        Zll, csrLl, cntLl, curLl, out_label);

    // Supervision-edge dot products.
    pred_kernel<<<(ELBL * 32) / 256, 256, 0, stream>>>(
        out_title, out_label, el_src, el_dst, pred, ELBL);
}